// Round 1
// baseline (115.845 us; speedup 1.0000x reference)
//
#include <hip/hip_runtime.h>

#define NL 12
#define NB 2
#define NS 2048
#define ND 1024
#define NDK 256
#define NBS (NB*NS)   // 4096

typedef __attribute__((ext_vector_type(8))) short short8;
typedef __attribute__((ext_vector_type(4))) float floatx4;

__device__ __forceinline__ unsigned short f2bf(float f) {
    unsigned int u = __float_as_uint(f);
    u += 0x7FFFu + ((u >> 16) & 1u);
    return (unsigned short)(u >> 16);
}

__device__ __forceinline__ float wred(float v) {
#pragma unroll
    for (int off = 32; off > 0; off >>= 1) v += __shfl_down(v, off);
    return v;  // lane 0 holds the 64-lane sum
}

// Wq (DK x D fp32) -> Wqb bf16 same layout ( = B^T for Q GEMM, K=D )
// Wk (DK x D ... wait: Wk is (DK, D)? No: Wk is (DK=256, D=1024) rows k, cols d.
// For V = Q @ Wk_asB where B[k][n] uses k=DK index, n=D index: B[k][n] = Wk[k][n]? 
// Reference: keys = einsum('lbsd,kd->lbsk', norm, Wk), i.e. keys[k] = sum_d norm[d]*Wk[k,d].
// v[d] = sum_k Wk[k,d] * q[k]  ->  V = Q (BSxDK) @ Wk (DKxD)  with B[k][d] = Wk[k,d].
// Bt layout needed: Bt[d][k] = Wk[k][d]  (D x DK, k-contiguous).
__global__ void k_prep(const float* __restrict__ Wq, const float* __restrict__ Wk,
                       unsigned short* __restrict__ Wqb, unsigned short* __restrict__ Wkt) {
    int i = blockIdx.x * 256 + threadIdx.x;   // 0 .. DK*D-1
    Wqb[i] = f2bf(Wq[i]);
    int n = i >> 8;            // d index (0..1023),  i = n*NDK + k
    int k = i & (NDK - 1);     // k index (0..255)
    Wkt[i] = f2bf(Wk[(size_t)k * ND + n]);
}

// LayerNorm of states[11] -> U bf16 (NBS x ND)
__global__ void k_ln(const float* __restrict__ x11, const float* __restrict__ lnw,
                     const float* __restrict__ lnb, unsigned short* __restrict__ U) {
    __shared__ float red[8];
    const int p = blockIdx.x, tid = threadIdx.x;
    const float4* xr = (const float4*)(x11 + (size_t)p * ND);
    float4 x = xr[tid];
    float s1 = x.x + x.y + x.z + x.w;
    float s2 = x.x*x.x + x.y*x.y + x.z*x.z + x.w*x.w;
    s1 = wred(s1); s2 = wred(s2);
    int wv = tid >> 6;
    if ((tid & 63) == 0) { red[wv] = s1; red[4 + wv] = s2; }
    __syncthreads();
    float S1 = red[0] + red[1] + red[2] + red[3];
    float S2 = red[4] + red[5] + red[6] + red[7];
    float mu = S1 * (1.0f / ND);
    float var = S2 * (1.0f / ND) - mu * mu;
    float rstd = rsqrtf(var + 1e-5f);
    float4 w = ((const float4*)lnw)[tid];
    float4 b = ((const float4*)lnb)[tid];
    ushort4 u;
    u.x = f2bf((x.x - mu) * rstd * w.x + b.x);
    u.y = f2bf((x.y - mu) * rstd * w.y + b.y);
    u.z = f2bf((x.z - mu) * rstd * w.z + b.z);
    u.w = f2bf((x.w - mu) * rstd * w.w + b.w);
    ((ushort4*)U)[(size_t)p * (ND / 4) + tid] = u;
}

// C (M x N) = A (M x K, bf16 row-major) @ Bt^T  (Bt is N x K bf16 row-major)
// one wave per 16x16 output tile, mfma_f32_16x16x32_bf16
template<int N, int K, bool OUT_BF16>
__global__ void k_gemm(const unsigned short* __restrict__ A,
                       const unsigned short* __restrict__ Bt,
                       void* __restrict__ Cout) {
    const int wid = (blockIdx.x * blockDim.x + threadIdx.x) >> 6;
    const int lane = threadIdx.x & 63;
    const int TN = N / 16;
    const int tm = wid / TN, tn = wid % TN;
    const int lr = lane & 15;
    const int kh = lane >> 4;   // 0..3  -> k offset kh*8
    // A frag: lane holds A[tm*16 + lr][kb*32 + kh*8 + j], j=0..7 (contiguous 16B)
    const short8* ap = (const short8*)(A + (size_t)(tm * 16 + lr) * K + kh * 8);
    // B frag: lane holds B[kb*32 + kh*8 + j][tn*16 + lr] = Bt[tn*16+lr][k...]
    const short8* bp = (const short8*)(Bt + (size_t)(tn * 16 + lr) * K + kh * 8);
    floatx4 acc = {0.f, 0.f, 0.f, 0.f};
#pragma unroll 4
    for (int kb = 0; kb < K / 32; ++kb) {
        short8 a = ap[kb * 4];
        short8 b = bp[kb * 4];
        acc = __builtin_amdgcn_mfma_f32_16x16x32_bf16(a, b, acc, 0, 0, 0);
    }
    // D: row = tm*16 + kh*4 + r, col = tn*16 + lr
    const int orow = tm * 16 + kh * 4;
    const int ocol = tn * 16 + lr;
    if constexpr (OUT_BF16) {
        unsigned short* C = (unsigned short*)Cout;
#pragma unroll
        for (int r = 0; r < 4; ++r) C[(size_t)(orow + r) * N + ocol] = f2bf(acc[r]);
    } else {
        float* C = (float*)Cout;
#pragma unroll
        for (int r = 0; r < 4; ++r) C[(size_t)(orow + r) * N + ocol] = acc[r];
    }
}

// Fused: stream all 12 layers of one (b,s) row, compute LN-folded logits,
// softmax over depth, weighted mix (rows held in registers), gate, write out.
__global__ void k_fused(const float* __restrict__ states, const float* __restrict__ V,
                        const float* __restrict__ lnw, const float* __restrict__ lnb,
                        const float* __restrict__ gatep, float* __restrict__ out) {
    __shared__ float s_logit[12];
    __shared__ float s_w12[12];
    __shared__ float s_g;
    __shared__ float s_part[4][ND];
    __shared__ float s_x11[ND];
    const int p = blockIdx.x;          // (b,s) flat: row offset p*ND, layer stride NBS*ND
    const int tid = threadIdx.x;
    const int lane = tid & 63;
    const int wv = tid >> 6;
    const size_t LS = (size_t)NBS * ND;
    const float* base = states + (size_t)p * ND;
    const float4* Vp = (const float4*)(V + (size_t)p * ND);

    // t = lnw * v  (kept in regs), c1 = sum(t), c2 = sum(lnb * v)
    float4 t[4];
    float c1 = 0.f, c2 = 0.f;
#pragma unroll
    for (int i = 0; i < 4; ++i) {
        int idx = lane + 64 * i;
        float4 v = Vp[idx];
        float4 w = ((const float4*)lnw)[idx];
        float4 b = ((const float4*)lnb)[idx];
        float4 tt; tt.x = v.x*w.x; tt.y = v.y*w.y; tt.z = v.z*w.z; tt.w = v.w*w.w;
        t[i] = tt;
        c1 += tt.x + tt.y + tt.z + tt.w;
        c2 += v.x*b.x + v.y*b.y + v.z*b.z + v.w*b.w;
    }
    c1 = wred(c1); c2 = wred(c2);   // valid in lane 0 (only lane 0 uses them)

    // wave wv owns layers wv, wv+4, wv+8 ; rows held in registers
    float4 x[3][4];
#pragma unroll
    for (int rr = 0; rr < 3; ++rr) {
        const int l = wv + 4 * rr;
        const float4* xr = (const float4*)(base + (size_t)l * LS);
        float s1 = 0.f, s2 = 0.f, s3 = 0.f;
#pragma unroll
        for (int i = 0; i < 4; ++i) {
            float4 xx = xr[lane + 64 * i];
            x[rr][i] = xx;
            s1 += xx.x + xx.y + xx.z + xx.w;
            s2 += xx.x*xx.x + xx.y*xx.y + xx.z*xx.z + xx.w*xx.w;
            s3 += xx.x*t[i].x + xx.y*t[i].y + xx.z*t[i].z + xx.w*t[i].w;
        }
        s1 = wred(s1); s2 = wred(s2); s3 = wred(s3);
        if (lane == 0) {
            float mu = s1 * (1.0f / ND);
            float var = s2 * (1.0f / ND) - mu * mu;
            float rstd = rsqrtf(var + 1e-5f);
            s_logit[l] = 0.0625f * (rstd * (s3 - mu * c1) + c2);   // 1/sqrt(DK)=1/16
        }
    }
    __syncthreads();
    if (tid == 0) {
        float mx = s_logit[0];
#pragma unroll
        for (int l = 1; l < 12; ++l) mx = fmaxf(mx, s_logit[l]);
        float e[12], sum = 0.f;
#pragma unroll
        for (int l = 0; l < 12; ++l) { e[l] = expf(s_logit[l] - mx); sum += e[l]; }
        float inv = 1.0f / sum;
#pragma unroll
        for (int l = 0; l < 12; ++l) s_w12[l] = e[l] * inv;
        s_g = 1.0f / (1.0f + expf(-gatep[0]));
    }
    __syncthreads();

    // per-wave partial mixed from registers
    const float w0 = s_w12[wv], w1 = s_w12[wv + 4], w2 = s_w12[wv + 8];
#pragma unroll
    for (int i = 0; i < 4; ++i) {
        int idx = lane + 64 * i;
        float4 pm;
        pm.x = w0*x[0][i].x + w1*x[1][i].x + w2*x[2][i].x;
        pm.y = w0*x[0][i].y + w1*x[1][i].y + w2*x[2][i].y;
        pm.z = w0*x[0][i].z + w1*x[1][i].z + w2*x[2][i].z;
        pm.w = w0*x[0][i].w + w1*x[1][i].w + w2*x[2][i].w;
        ((float4*)s_part[wv])[idx] = pm;
        if (wv == 3) ((float4*)s_x11)[idx] = x[2][i];   // wv=3, rr=2 -> l=11
    }
    __syncthreads();

    const float g = s_g;
    float4 m, x11, o;
    const float4* p0 = (const float4*)s_part[0];
    const float4* p1 = (const float4*)s_part[1];
    const float4* p2 = (const float4*)s_part[2];
    const float4* p3 = (const float4*)s_part[3];
    float4 a0 = p0[tid], a1 = p1[tid], a2 = p2[tid], a3 = p3[tid];
    m.x = a0.x + a1.x + a2.x + a3.x;
    m.y = a0.y + a1.y + a2.y + a3.y;
    m.z = a0.z + a1.z + a2.z + a3.z;
    m.w = a0.w + a1.w + a2.w + a3.w;
    x11 = ((const float4*)s_x11)[tid];
    o.x = g * x11.x + (1.f - g) * m.x;
    o.y = g * x11.y + (1.f - g) * m.y;
    o.z = g * x11.z + (1.f - g) * m.z;
    o.w = g * x11.w + (1.f - g) * m.w;
    ((float4*)(out + (size_t)p * ND))[tid] = o;
}

extern "C" void kernel_launch(void* const* d_in, const int* in_sizes, int n_in,
                              void* d_out, int out_size, void* d_ws, size_t ws_size,
                              hipStream_t stream) {
    (void)in_sizes; (void)n_in; (void)out_size; (void)ws_size;
    const float* states = (const float*)d_in[0];
    const float* Wq     = (const float*)d_in[1];
    const float* Wk     = (const float*)d_in[2];
    const float* lnw    = (const float*)d_in[3];
    const float* lnb    = (const float*)d_in[4];
    const float* gate   = (const float*)d_in[5];
    float* out = (float*)d_out;
    char* ws = (char*)d_ws;

    unsigned short* U   = (unsigned short*)(ws);                          // 8 MB  (NBS x ND bf16)
    unsigned short* Wqb = (unsigned short*)(ws + (8u  << 20));            // 512 KB
    unsigned short* Wkt = (unsigned short*)(ws + (8u  << 20) + (1u<<19)); // 512 KB
    unsigned short* Q   = (unsigned short*)(ws + (9u  << 20));            // 2 MB  (NBS x DK bf16)
    float*          V   = (float*)        (ws + (11u << 20));             // 16 MB (NBS x ND f32)

    k_prep<<<dim3((NDK * ND) / 256), dim3(256), 0, stream>>>(Wq, Wk, Wqb, Wkt);
    k_ln<<<dim3(NBS), dim3(256), 0, stream>>>(states + (size_t)(NL - 1) * NBS * ND, lnw, lnb, U);
    // Q (NBS x NDK) = U (NBS x ND) @ Wq^T   ; Bt = Wqb (NDK x ND)
    k_gemm<NDK, ND, true><<<dim3((NBS / 16) * (NDK / 16) / 4), dim3(256), 0, stream>>>(U, Wqb, Q);
    // V (NBS x ND) = Q (NBS x NDK) @ Wk     ; Bt = Wkt (ND x NDK)
    k_gemm<ND, NDK, false><<<dim3((NBS / 16) * (ND / 16) / 4), dim3(256), 0, stream>>>(Q, Wkt, V);
    k_fused<<<dim3(NBS), dim3(256), 0, stream>>>(states, V, lnw, lnb, gate, out);
}

// Round 2
// 95.080 us; speedup vs baseline: 1.2184x; 1.2184x over previous
//
#include <hip/hip_runtime.h>

#define NL 12
#define NB 2
#define NS 2048
#define ND 1024
#define NDK 256
#define NBS (NB*NS)   // 4096

typedef __attribute__((ext_vector_type(8))) short short8;
typedef __attribute__((ext_vector_type(4))) float floatx4;

__device__ __forceinline__ unsigned short f2bf(float f) {
    unsigned int u = __float_as_uint(f);
    u += 0x7FFFu + ((u >> 16) & 1u);
    return (unsigned short)(u >> 16);
}

// all-lanes 64-wide butterfly sum
__device__ __forceinline__ float wredx(float v) {
#pragma unroll
    for (int m = 32; m > 0; m >>= 1) v += __shfl_xor(v, m);
    return v;
}

// Merged: blocks [0,1024) do weight prep; blocks [1024,5120) do LN of layer 11.
// Wq (DK x D fp32) -> Wqb bf16 same layout (Bt for Q GEMM, K=D)
// Wk (DK x D fp32) -> Wkt bf16 transposed: Wkt[d][k] = Wk[k][d]  (D x DK)
__global__ void k_prep_ln(const float* __restrict__ Wq, const float* __restrict__ Wk,
                          const float* __restrict__ x11,
                          const float* __restrict__ lnw, const float* __restrict__ lnb,
                          unsigned short* __restrict__ Wqb, unsigned short* __restrict__ Wkt,
                          unsigned short* __restrict__ U) {
    const int tid = threadIdx.x;
    if (blockIdx.x < (NDK * ND) / 256) {
        int i = blockIdx.x * 256 + tid;      // 0 .. DK*D-1
        Wqb[i] = f2bf(Wq[i]);
        int n = i >> 8;                      // d index
        int k = i & (NDK - 1);               // k index
        Wkt[i] = f2bf(Wk[(size_t)k * ND + n]);
        return;
    }
    __shared__ float red[8];
    const int p = blockIdx.x - (NDK * ND) / 256;
    const float4* xr = (const float4*)(x11 + (size_t)p * ND);
    float4 x = xr[tid];
    float s1 = wredx(x.x + x.y + x.z + x.w);
    float s2 = wredx(x.x*x.x + x.y*x.y + x.z*x.z + x.w*x.w);
    int wv = tid >> 6;
    if ((tid & 63) == 0) { red[wv] = s1; red[4 + wv] = s2; }
    __syncthreads();
    float S1 = red[0] + red[1] + red[2] + red[3];
    float S2 = red[4] + red[5] + red[6] + red[7];
    float mu = S1 * (1.0f / ND);
    float var = S2 * (1.0f / ND) - mu * mu;
    float rstd = rsqrtf(var + 1e-5f);
    float4 w = ((const float4*)lnw)[tid];
    float4 b = ((const float4*)lnb)[tid];
    ushort4 u;
    u.x = f2bf((x.x - mu) * rstd * w.x + b.x);
    u.y = f2bf((x.y - mu) * rstd * w.y + b.y);
    u.z = f2bf((x.z - mu) * rstd * w.z + b.z);
    u.w = f2bf((x.w - mu) * rstd * w.w + b.w);
    ((ushort4*)U)[(size_t)p * (ND / 4) + tid] = u;
}

// C (M x N) = A (M x K bf16 row-major) @ Bt^T  (Bt is N x K bf16 row-major)
// one wave per 16 x (16*CT) output tile; A-frag reused CT times per K-step.
template<int N, int K, int CT, bool OUT_BF16>
__global__ void k_gemm(const unsigned short* __restrict__ A,
                       const unsigned short* __restrict__ Bt,
                       void* __restrict__ Cout) {
    const int wid = (blockIdx.x * blockDim.x + threadIdx.x) >> 6;
    const int lane = threadIdx.x & 63;
    const int TNB = N / (16 * CT);
    const int tm = wid / TNB, tnb = wid % TNB;
    const int lr = lane & 15;
    const int kh = lane >> 4;   // 0..3  -> k offset kh*8
    const short8* ap = (const short8*)(A + (size_t)(tm * 16 + lr) * K + kh * 8);
    const short8* bp[CT];
#pragma unroll
    for (int c = 0; c < CT; ++c)
        bp[c] = (const short8*)(Bt + (size_t)(tnb * CT * 16 + c * 16 + lr) * K + kh * 8);
    floatx4 acc[CT];
#pragma unroll
    for (int c = 0; c < CT; ++c) acc[c] = (floatx4){0.f, 0.f, 0.f, 0.f};
#pragma unroll 4
    for (int kb = 0; kb < K / 32; ++kb) {
        short8 a = ap[kb * 4];
#pragma unroll
        for (int c = 0; c < CT; ++c) {
            short8 b = bp[c][kb * 4];
            acc[c] = __builtin_amdgcn_mfma_f32_16x16x32_bf16(a, b, acc[c], 0, 0, 0);
        }
    }
    // D: row = tm*16 + kh*4 + r, col = tnb*CT*16 + c*16 + lr
    const int orow = tm * 16 + kh * 4;
#pragma unroll
    for (int c = 0; c < CT; ++c) {
        const int ocol = tnb * CT * 16 + c * 16 + lr;
        if constexpr (OUT_BF16) {
            unsigned short* C = (unsigned short*)Cout;
#pragma unroll
            for (int r = 0; r < 4; ++r) C[(size_t)(orow + r) * N + ocol] = f2bf(acc[c][r]);
        } else {
            float* C = (float*)Cout;
#pragma unroll
            for (int r = 0; r < 4; ++r) C[(size_t)(orow + r) * N + ocol] = acc[c][r];
        }
    }
}

// Fused: stream all 12 layers of one (b,s) row, LN-folded logits, softmax over
// depth, weighted mix from registers, gate, write out.
// All 11 partial sums accumulated first, then one interleaved butterfly pass.
__global__ void k_fused(const float* __restrict__ states, const float* __restrict__ V,
                        const float* __restrict__ lnw, const float* __restrict__ lnb,
                        const float* __restrict__ gatep, float* __restrict__ out) {
    __shared__ float s_logit[12];
    __shared__ float s_w12[12];
    __shared__ float s_g;
    __shared__ float s_part[4][ND];
    __shared__ float s_x11[ND];
    const int p = blockIdx.x;
    const int tid = threadIdx.x;
    const int lane = tid & 63;
    const int wv = tid >> 6;
    const size_t LS = (size_t)NBS * ND;
    const float* base = states + (size_t)p * ND;
    const float4* Vp = (const float4*)(V + (size_t)p * ND);

    // t = lnw * v (regs); partials: red[9] = c1 = sum(t), red[10] = c2 = sum(lnb*v)
    float4 t[4];
    float red[11];
#pragma unroll
    for (int j = 0; j < 11; ++j) red[j] = 0.f;
#pragma unroll
    for (int i = 0; i < 4; ++i) {
        int idx = lane + 64 * i;
        float4 v = Vp[idx];
        float4 w = ((const float4*)lnw)[idx];
        float4 b = ((const float4*)lnb)[idx];
        float4 tt; tt.x = v.x*w.x; tt.y = v.y*w.y; tt.z = v.z*w.z; tt.w = v.w*w.w;
        t[i] = tt;
        red[9]  += tt.x + tt.y + tt.z + tt.w;
        red[10] += v.x*b.x + v.y*b.y + v.z*b.z + v.w*b.w;
    }

    // wave wv owns layers wv, wv+4, wv+8; rows in registers; sums deferred
    float4 x[3][4];
#pragma unroll
    for (int rr = 0; rr < 3; ++rr) {
        const int l = wv + 4 * rr;
        const float4* xr = (const float4*)(base + (size_t)l * LS);
#pragma unroll
        for (int i = 0; i < 4; ++i) {
            float4 xx = xr[lane + 64 * i];
            x[rr][i] = xx;
            red[rr]     += xx.x + xx.y + xx.z + xx.w;
            red[3 + rr] += xx.x*xx.x + xx.y*xx.y + xx.z*xx.z + xx.w*xx.w;
            red[6 + rr] += xx.x*t[i].x + xx.y*t[i].y + xx.z*t[i].z + xx.w*t[i].w;
        }
    }
    // one interleaved butterfly over all 11 sums (ILP across chains)
#pragma unroll
    for (int m = 32; m > 0; m >>= 1) {
#pragma unroll
        for (int j = 0; j < 11; ++j) red[j] += __shfl_xor(red[j], m);
    }
    if (lane == 0) {
#pragma unroll
        for (int rr = 0; rr < 3; ++rr) {
            float mu = red[rr] * (1.0f / ND);
            float var = red[3 + rr] * (1.0f / ND) - mu * mu;
            float rstd = rsqrtf(var + 1e-5f);
            s_logit[wv + 4 * rr] = 0.0625f * (rstd * (red[6 + rr] - mu * red[9]) + red[10]);
        }
    }
    __syncthreads();
    if (tid == 0) {
        float mx = s_logit[0];
#pragma unroll
        for (int l = 1; l < 12; ++l) mx = fmaxf(mx, s_logit[l]);
        float e[12], sum = 0.f;
#pragma unroll
        for (int l = 0; l < 12; ++l) { e[l] = expf(s_logit[l] - mx); sum += e[l]; }
        float inv = 1.0f / sum;
#pragma unroll
        for (int l = 0; l < 12; ++l) s_w12[l] = e[l] * inv;
        s_g = 1.0f / (1.0f + expf(-gatep[0]));
    }
    __syncthreads();

    const float w0 = s_w12[wv], w1 = s_w12[wv + 4], w2 = s_w12[wv + 8];
#pragma unroll
    for (int i = 0; i < 4; ++i) {
        int idx = lane + 64 * i;
        float4 pm;
        pm.x = w0*x[0][i].x + w1*x[1][i].x + w2*x[2][i].x;
        pm.y = w0*x[0][i].y + w1*x[1][i].y + w2*x[2][i].y;
        pm.z = w0*x[0][i].z + w1*x[1][i].z + w2*x[2][i].z;
        pm.w = w0*x[0][i].w + w1*x[1][i].w + w2*x[2][i].w;
        ((float4*)s_part[wv])[idx] = pm;
        if (wv == 3) ((float4*)s_x11)[idx] = x[2][i];   // wv=3, rr=2 -> l=11
    }
    __syncthreads();

    const float g = s_g;
    float4 a0 = ((const float4*)s_part[0])[tid];
    float4 a1 = ((const float4*)s_part[1])[tid];
    float4 a2 = ((const float4*)s_part[2])[tid];
    float4 a3 = ((const float4*)s_part[3])[tid];
    float4 x11 = ((const float4*)s_x11)[tid];
    float4 o;
    o.x = g * x11.x + (1.f - g) * (a0.x + a1.x + a2.x + a3.x);
    o.y = g * x11.y + (1.f - g) * (a0.y + a1.y + a2.y + a3.y);
    o.z = g * x11.z + (1.f - g) * (a0.z + a1.z + a2.z + a3.z);
    o.w = g * x11.w + (1.f - g) * (a0.w + a1.w + a2.w + a3.w);
    ((float4*)(out + (size_t)p * ND))[tid] = o;
}

extern "C" void kernel_launch(void* const* d_in, const int* in_sizes, int n_in,
                              void* d_out, int out_size, void* d_ws, size_t ws_size,
                              hipStream_t stream) {
    (void)in_sizes; (void)n_in; (void)out_size; (void)ws_size;
    const float* states = (const float*)d_in[0];
    const float* Wq     = (const float*)d_in[1];
    const float* Wk     = (const float*)d_in[2];
    const float* lnw    = (const float*)d_in[3];
    const float* lnb    = (const float*)d_in[4];
    const float* gate   = (const float*)d_in[5];
    float* out = (float*)d_out;
    char* ws = (char*)d_ws;

    unsigned short* U   = (unsigned short*)(ws);                          // 8 MB  (NBS x ND bf16)
    unsigned short* Wqb = (unsigned short*)(ws + (8u  << 20));            // 512 KB
    unsigned short* Wkt = (unsigned short*)(ws + (8u  << 20) + (1u<<19)); // 512 KB
    unsigned short* Q   = (unsigned short*)(ws + (9u  << 20));            // 2 MB  (NBS x DK bf16)
    float*          V   = (float*)        (ws + (11u << 20));             // 16 MB (NBS x ND f32)

    k_prep_ln<<<dim3((NDK * ND) / 256 + NBS), dim3(256), 0, stream>>>(
        Wq, Wk, states + (size_t)(NL - 1) * NBS * ND, lnw, lnb, Wqb, Wkt, U);
    // Q (NBS x NDK) = U (NBS x ND) @ Wq^T ; Bt = Wqb (NDK x ND); CT=2 -> 2048 waves
    k_gemm<NDK, ND, 2, true><<<dim3((NBS / 16) * (NDK / 32) / 4), dim3(256), 0, stream>>>(U, Wqb, Q);
    // V (NBS x ND) = Q (NBS x NDK) @ Wk  ; Bt = Wkt (ND x NDK); CT=4 -> 4096 waves
    k_gemm<ND, NDK, 4, false><<<dim3((NBS / 16) * (ND / 64) / 4), dim3(256), 0, stream>>>(Q, Wkt, V);
    k_fused<<<dim3(NBS), dim3(256), 0, stream>>>(states, V, lnw, lnb, gate, out);
}

// Round 3
// 77.089 us; speedup vs baseline: 1.5027x; 1.2334x over previous
//
#include <hip/hip_runtime.h>

#define NL 12
#define NB 2
#define NS 2048
#define ND 1024
#define NDK 256
#define NBS (NB*NS)   // 4096

typedef __attribute__((ext_vector_type(8))) short short8;
typedef __attribute__((ext_vector_type(4))) float floatx4;

__device__ __forceinline__ unsigned short f2bf(float f) {
    unsigned int u = __float_as_uint(f);
    u += 0x7FFFu + ((u >> 16) & 1u);
    return (unsigned short)(u >> 16);
}
__device__ __forceinline__ short f2bfs(float f) { return (short)f2bf(f); }

// K1: blocks [0,256): W2t[d][d'] = sum_k Wk[k][d]*Wq[k][d']  (bf16 out, MFMA)
//     blocks [256, 256+4096): LayerNorm(states[11]) -> U bf16
__global__ void k_prep_ln(const float* __restrict__ Wq, const float* __restrict__ Wk,
                          const float* __restrict__ x11,
                          const float* __restrict__ lnw, const float* __restrict__ lnb,
                          unsigned short* __restrict__ W2t, unsigned short* __restrict__ U) {
    const int tid = threadIdx.x;
    if (blockIdx.x < 256) {
        const int lane = tid & 63, wv = tid >> 6;
        const int wid = blockIdx.x * 4 + wv;      // 0..1023
        const int tm = wid >> 4;                  // d-tile (rows of W2t), 0..63
        const int tnb = wid & 15;                 // d'-tile (cols, 64 wide), 0..15
        const int lr = lane & 15, kh = lane >> 4;
        floatx4 acc[4];
#pragma unroll
        for (int c = 0; c < 4; ++c) acc[c] = (floatx4){0.f, 0.f, 0.f, 0.f};
#pragma unroll 2
        for (int kb = 0; kb < 8; ++kb) {
            const float* Ab = Wk + (size_t)(kb * 32 + kh * 8) * ND + tm * 16 + lr;
            const float* Bb = Wq + (size_t)(kb * 32 + kh * 8) * ND + tnb * 64 + lr;
            short8 a;
#pragma unroll
            for (int j = 0; j < 8; ++j) a[j] = f2bfs(Ab[(size_t)j * ND]);
#pragma unroll
            for (int c = 0; c < 4; ++c) {
                short8 b;
#pragma unroll
                for (int j = 0; j < 8; ++j) b[j] = f2bfs(Bb[(size_t)j * ND + c * 16]);
                acc[c] = __builtin_amdgcn_mfma_f32_16x16x32_bf16(a, b, acc[c], 0, 0, 0);
            }
        }
#pragma unroll
        for (int c = 0; c < 4; ++c)
#pragma unroll
            for (int r = 0; r < 4; ++r)
                W2t[(size_t)(tm * 16 + kh * 4 + r) * ND + tnb * 64 + c * 16 + lr] = f2bf(acc[c][r]);
        return;
    }
    __shared__ float red[8];
    const int p = blockIdx.x - 256;
    const float4* xr = (const float4*)(x11 + (size_t)p * ND);
    float4 x = xr[tid];
    float s1 = x.x + x.y + x.z + x.w;
    float s2 = x.x*x.x + x.y*x.y + x.z*x.z + x.w*x.w;
#pragma unroll
    for (int m = 32; m > 0; m >>= 1) { s1 += __shfl_xor(s1, m); s2 += __shfl_xor(s2, m); }
    int wv = tid >> 6;
    if ((tid & 63) == 0) { red[wv] = s1; red[4 + wv] = s2; }
    __syncthreads();
    float S1 = red[0] + red[1] + red[2] + red[3];
    float S2 = red[4] + red[5] + red[6] + red[7];
    float mu = S1 * (1.0f / ND);
    float var = S2 * (1.0f / ND) - mu * mu;
    float rstd = rsqrtf(var + 1e-5f);
    float4 w = ((const float4*)lnw)[tid];
    float4 b = ((const float4*)lnb)[tid];
    ushort4 u;
    u.x = f2bf((x.x - mu) * rstd * w.x + b.x);
    u.y = f2bf((x.y - mu) * rstd * w.y + b.y);
    u.z = f2bf((x.z - mu) * rstd * w.z + b.z);
    u.w = f2bf((x.w - mu) * rstd * w.w + b.w);
    ((ushort4*)U)[(size_t)p * (ND / 4) + tid] = u;
}

// K2: V (4096 x 1024 fp32) = U (4096 x 1024 bf16) @ W2t^T (W2t is 1024 x 1024 bf16, [d][d'])
// 128x128 block tile, BK=64, 4 waves (2x2) x 64x64 wave tiles, reg-staged padded LDS.
#define BM 128
#define BN 128
#define BK 64
#define LDP 72   // padded row length (elements): conflict-free ds_read_b128
__global__ __launch_bounds__(256) void k_vgemm(const unsigned short* __restrict__ U,
                                               const unsigned short* __restrict__ W2t,
                                               float* __restrict__ V) {
    __shared__ short8 AsV[(BM * LDP) / 8];
    __shared__ short8 BsV[(BN * LDP) / 8];
    unsigned short* As = (unsigned short*)AsV;
    unsigned short* Bs = (unsigned short*)BsV;
    const int tid = threadIdx.x;
    const int lane = tid & 63;
    const int wv = tid >> 6;
    const int wr = wv >> 1, wc = wv & 1;
    const int lr = lane & 15, kh = lane >> 4;
    const int bm0 = (blockIdx.x >> 3) * BM;   // 32 m-tiles
    const int bn0 = (blockIdx.x & 7) * BN;    // 8 n-tiles
    // staging: thread -> (row, half): 2 threads cover one 64-elem row of the K-tile
    const int srow = tid >> 1, shalf = tid & 1;
    const short8* gA = (const short8*)(U   + (size_t)(bm0 + srow) * ND + shalf * 32);
    const short8* gB = (const short8*)(W2t + (size_t)(bn0 + srow) * ND + shalf * 32);
    const int sBase = srow * LDP + shalf * 32;   // element offset in LDS tile

    floatx4 acc[4][4];
#pragma unroll
    for (int m = 0; m < 4; ++m)
#pragma unroll
        for (int n = 0; n < 4; ++n) acc[m][n] = (floatx4){0.f, 0.f, 0.f, 0.f};

    short8 ra[4], rb[4];
#pragma unroll
    for (int j = 0; j < 4; ++j) { ra[j] = gA[j]; rb[j] = gB[j]; }   // tile 0

    const int NT = 1024 / BK;   // 16
#pragma unroll 1
    for (int t = 0; t < NT; ++t) {
        __syncthreads();   // previous tile's readers done
#pragma unroll
        for (int j = 0; j < 4; ++j) {
            *(short8*)&As[sBase + j * 8] = ra[j];
            *(short8*)&Bs[sBase + j * 8] = rb[j];
        }
        __syncthreads();   // tile visible
        if (t < NT - 1) {
#pragma unroll
            for (int j = 0; j < 4; ++j) { ra[j] = gA[(t + 1) * 8 + j]; rb[j] = gB[(t + 1) * 8 + j]; }
        }
#pragma unroll
        for (int kk = 0; kk < 2; ++kk) {
            short8 a[4], b[4];
#pragma unroll
            for (int m = 0; m < 4; ++m)
                a[m] = *(const short8*)&As[(wr * 64 + m * 16 + lr) * LDP + kk * 32 + kh * 8];
#pragma unroll
            for (int n = 0; n < 4; ++n)
                b[n] = *(const short8*)&Bs[(wc * 64 + n * 16 + lr) * LDP + kk * 32 + kh * 8];
#pragma unroll
            for (int m = 0; m < 4; ++m)
#pragma unroll
                for (int n = 0; n < 4; ++n)
                    acc[m][n] = __builtin_amdgcn_mfma_f32_16x16x32_bf16(a[m], b[n], acc[m][n], 0, 0, 0);
        }
    }
#pragma unroll
    for (int m = 0; m < 4; ++m)
#pragma unroll
        for (int n = 0; n < 4; ++n)
#pragma unroll
            for (int r = 0; r < 4; ++r)
                V[(size_t)(bm0 + wr * 64 + m * 16 + kh * 4 + r) * ND + bn0 + wc * 64 + n * 16 + lr]
                    = acc[m][n][r];
}

// K3: stream all 12 layers per (b,s) row; LN-folded logits; softmax over depth;
// register-held weighted mix; gate; write out.
__global__ void k_fused(const float* __restrict__ states, const float* __restrict__ V,
                        const float* __restrict__ lnw, const float* __restrict__ lnb,
                        const float* __restrict__ gatep, float* __restrict__ out) {
    __shared__ float s_logit[12];
    __shared__ float s_w12[12];
    __shared__ float s_g;
    __shared__ float s_part[4][ND];
    __shared__ float s_x11[ND];
    const int p = blockIdx.x;
    const int tid = threadIdx.x;
    const int lane = tid & 63;
    const int wv = tid >> 6;
    const size_t LS = (size_t)NBS * ND;
    const float* base = states + (size_t)p * ND;
    const float4* Vp = (const float4*)(V + (size_t)p * ND);

    float4 t[4];
    float red[11];
#pragma unroll
    for (int j = 0; j < 11; ++j) red[j] = 0.f;
#pragma unroll
    for (int i = 0; i < 4; ++i) {
        int idx = lane + 64 * i;
        float4 v = Vp[idx];
        float4 w = ((const float4*)lnw)[idx];
        float4 b = ((const float4*)lnb)[idx];
        float4 tt; tt.x = v.x*w.x; tt.y = v.y*w.y; tt.z = v.z*w.z; tt.w = v.w*w.w;
        t[i] = tt;
        red[9]  += tt.x + tt.y + tt.z + tt.w;
        red[10] += v.x*b.x + v.y*b.y + v.z*b.z + v.w*b.w;
    }

    float4 x[3][4];
#pragma unroll
    for (int rr = 0; rr < 3; ++rr) {
        const int l = wv + 4 * rr;
        const float4* xr = (const float4*)(base + (size_t)l * LS);
#pragma unroll
        for (int i = 0; i < 4; ++i) {
            float4 xx = xr[lane + 64 * i];
            x[rr][i] = xx;
            red[rr]     += xx.x + xx.y + xx.z + xx.w;
            red[3 + rr] += xx.x*xx.x + xx.y*xx.y + xx.z*xx.z + xx.w*xx.w;
            red[6 + rr] += xx.x*t[i].x + xx.y*t[i].y + xx.z*t[i].z + xx.w*t[i].w;
        }
    }
#pragma unroll
    for (int m = 32; m > 0; m >>= 1) {
#pragma unroll
        for (int j = 0; j < 11; ++j) red[j] += __shfl_xor(red[j], m);
    }
    if (lane == 0) {
#pragma unroll
        for (int rr = 0; rr < 3; ++rr) {
            float mu = red[rr] * (1.0f / ND);
            float var = red[3 + rr] * (1.0f / ND) - mu * mu;
            float rstd = rsqrtf(var + 1e-5f);
            s_logit[wv + 4 * rr] = 0.0625f * (rstd * (red[6 + rr] - mu * red[9]) + red[10]);
        }
    }
    __syncthreads();
    if (tid == 0) {
        float mx = s_logit[0];
#pragma unroll
        for (int l = 1; l < 12; ++l) mx = fmaxf(mx, s_logit[l]);
        float e[12], sum = 0.f;
#pragma unroll
        for (int l = 0; l < 12; ++l) { e[l] = expf(s_logit[l] - mx); sum += e[l]; }
        float inv = 1.0f / sum;
#pragma unroll
        for (int l = 0; l < 12; ++l) s_w12[l] = e[l] * inv;
        s_g = 1.0f / (1.0f + expf(-gatep[0]));
    }
    __syncthreads();

    const float w0 = s_w12[wv], w1 = s_w12[wv + 4], w2 = s_w12[wv + 8];
#pragma unroll
    for (int i = 0; i < 4; ++i) {
        int idx = lane + 64 * i;
        float4 pm;
        pm.x = w0*x[0][i].x + w1*x[1][i].x + w2*x[2][i].x;
        pm.y = w0*x[0][i].y + w1*x[1][i].y + w2*x[2][i].y;
        pm.z = w0*x[0][i].z + w1*x[1][i].z + w2*x[2][i].z;
        pm.w = w0*x[0][i].w + w1*x[1][i].w + w2*x[2][i].w;
        ((float4*)s_part[wv])[idx] = pm;
        if (wv == 3) ((float4*)s_x11)[idx] = x[2][i];   // wv=3, rr=2 -> l=11
    }
    __syncthreads();

    const float g = s_g;
    float4 a0 = ((const float4*)s_part[0])[tid];
    float4 a1 = ((const float4*)s_part[1])[tid];
    float4 a2 = ((const float4*)s_part[2])[tid];
    float4 a3 = ((const float4*)s_part[3])[tid];
    float4 x11 = ((const float4*)s_x11)[tid];
    float4 o;
    o.x = g * x11.x + (1.f - g) * (a0.x + a1.x + a2.x + a3.x);
    o.y = g * x11.y + (1.f - g) * (a0.y + a1.y + a2.y + a3.y);
    o.z = g * x11.z + (1.f - g) * (a0.z + a1.z + a2.z + a3.z);
    o.w = g * x11.w + (1.f - g) * (a0.w + a1.w + a2.w + a3.w);
    ((float4*)(out + (size_t)p * ND))[tid] = o;
}

extern "C" void kernel_launch(void* const* d_in, const int* in_sizes, int n_in,
                              void* d_out, int out_size, void* d_ws, size_t ws_size,
                              hipStream_t stream) {
    (void)in_sizes; (void)n_in; (void)out_size; (void)ws_size;
    const float* states = (const float*)d_in[0];
    const float* Wq     = (const float*)d_in[1];
    const float* Wk     = (const float*)d_in[2];
    const float* lnw    = (const float*)d_in[3];
    const float* lnb    = (const float*)d_in[4];
    const float* gate   = (const float*)d_in[5];
    float* out = (float*)d_out;
    char* ws = (char*)d_ws;

    unsigned short* U   = (unsigned short*)(ws);               // 8.4 MB (NBS x ND bf16)
    unsigned short* W2t = (unsigned short*)(ws + (9u << 20));  // 2 MB   (ND x ND bf16)
    float*          V   = (float*)        (ws + (12u << 20));  // 16.8 MB (NBS x ND f32)

    k_prep_ln<<<dim3(256 + NBS), dim3(256), 0, stream>>>(
        Wq, Wk, states + (size_t)(NL - 1) * NBS * ND, lnw, lnb, W2t, U);
    k_vgemm<<<dim3((NBS / BM) * (ND / BN)), dim3(256), 0, stream>>>(U, W2t, V);
    k_fused<<<dim3(NBS), dim3(256), 0, stream>>>(states, V, lnw, lnb, gate, out);
}

// Round 4
// 75.430 us; speedup vs baseline: 1.5358x; 1.0220x over previous
//
#include <hip/hip_runtime.h>

#define NL 12
#define NB 2
#define NS 2048
#define ND 1024
#define NDK 256
#define NBS (NB*NS)   // 4096

typedef __attribute__((ext_vector_type(8))) short short8;
typedef __attribute__((ext_vector_type(4))) short short4v;
typedef __attribute__((ext_vector_type(4))) float floatx4;

__device__ __forceinline__ unsigned short f2bf(float f) {
    unsigned int u = __float_as_uint(f);
    u += 0x7FFFu + ((u >> 16) & 1u);
    return (unsigned short)(u >> 16);
}
__device__ __forceinline__ short f2bfs(float f) { return (short)f2bf(f); }
__device__ __forceinline__ float bf2f(short s) {
    return __uint_as_float(((unsigned int)(unsigned short)s) << 16);
}

// K1: blocks [0,256): W2t[d][d'] = sum_k Wk[k][d]*Wq[k][d']  (bf16 out, MFMA)
//     blocks [256, 256+4096): LayerNorm(states[11]) -> U bf16
__global__ void k_prep_ln(const float* __restrict__ Wq, const float* __restrict__ Wk,
                          const float* __restrict__ x11,
                          const float* __restrict__ lnw, const float* __restrict__ lnb,
                          unsigned short* __restrict__ W2t, unsigned short* __restrict__ U) {
    const int tid = threadIdx.x;
    if (blockIdx.x < 256) {
        const int lane = tid & 63, wv = tid >> 6;
        const int wid = blockIdx.x * 4 + wv;      // 0..1023
        const int tm = wid >> 4;                  // d-tile (rows of W2t), 0..63
        const int tnb = wid & 15;                 // d'-tile (cols, 64 wide), 0..15
        const int lr = lane & 15, kh = lane >> 4;
        floatx4 acc[4];
#pragma unroll
        for (int c = 0; c < 4; ++c) acc[c] = (floatx4){0.f, 0.f, 0.f, 0.f};
#pragma unroll 2
        for (int kb = 0; kb < 8; ++kb) {
            const float* Ab = Wk + (size_t)(kb * 32 + kh * 8) * ND + tm * 16 + lr;
            const float* Bb = Wq + (size_t)(kb * 32 + kh * 8) * ND + tnb * 64 + lr;
            short8 a;
#pragma unroll
            for (int j = 0; j < 8; ++j) a[j] = f2bfs(Ab[(size_t)j * ND]);
#pragma unroll
            for (int c = 0; c < 4; ++c) {
                short8 b;
#pragma unroll
                for (int j = 0; j < 8; ++j) b[j] = f2bfs(Bb[(size_t)j * ND + c * 16]);
                acc[c] = __builtin_amdgcn_mfma_f32_16x16x32_bf16(a, b, acc[c], 0, 0, 0);
            }
        }
#pragma unroll
        for (int c = 0; c < 4; ++c)
#pragma unroll
            for (int r = 0; r < 4; ++r)
                W2t[(size_t)(tm * 16 + kh * 4 + r) * ND + tnb * 64 + c * 16 + lr] = f2bf(acc[c][r]);
        return;
    }
    __shared__ float red[8];
    const int p = blockIdx.x - 256;
    const float4* xr = (const float4*)(x11 + (size_t)p * ND);
    float4 x = xr[tid];
    float s1 = x.x + x.y + x.z + x.w;
    float s2 = x.x*x.x + x.y*x.y + x.z*x.z + x.w*x.w;
#pragma unroll
    for (int m = 32; m > 0; m >>= 1) { s1 += __shfl_xor(s1, m); s2 += __shfl_xor(s2, m); }
    int wv = tid >> 6;
    if ((tid & 63) == 0) { red[wv] = s1; red[4 + wv] = s2; }
    __syncthreads();
    float S1 = red[0] + red[1] + red[2] + red[3];
    float S2 = red[4] + red[5] + red[6] + red[7];
    float mu = S1 * (1.0f / ND);
    float var = S2 * (1.0f / ND) - mu * mu;
    float rstd = rsqrtf(var + 1e-5f);
    float4 w = ((const float4*)lnw)[tid];
    float4 b = ((const float4*)lnb)[tid];
    ushort4 u;
    u.x = f2bf((x.x - mu) * rstd * w.x + b.x);
    u.y = f2bf((x.y - mu) * rstd * w.y + b.y);
    u.z = f2bf((x.z - mu) * rstd * w.z + b.z);
    u.w = f2bf((x.w - mu) * rstd * w.w + b.w);
    ((ushort4*)U)[(size_t)p * (ND / 4) + tid] = u;
}

// K2: V (4096 x 1024 bf16) = U (4096 x 1024 bf16) @ W2t^T (W2t is 1024 x 1024 bf16)
// 64x128 block tile, BK=64, 512 blocks (2/CU), 4 waves (2x2) x 32x64 wave tiles.
#define BM 64
#define BN 128
#define BK 64
#define LDP 72   // padded row length (elements)
__global__ __launch_bounds__(256) void k_vgemm(const unsigned short* __restrict__ U,
                                               const unsigned short* __restrict__ W2t,
                                               unsigned short* __restrict__ V) {
    __shared__ short8 AsV[(BM * LDP) / 8];
    __shared__ short8 BsV[(BN * LDP) / 8];
    unsigned short* As = (unsigned short*)AsV;
    unsigned short* Bs = (unsigned short*)BsV;
    const int tid = threadIdx.x;
    const int lane = tid & 63;
    const int wv = tid >> 6;
    const int wr = wv >> 1, wc = wv & 1;
    const int lr = lane & 15, kh = lane >> 4;
    const int bm0 = (blockIdx.x >> 3) * BM;   // 64 m-tiles
    const int bn0 = (blockIdx.x & 7) * BN;    // 8 n-tiles

    // staging maps: A 512 short8s (2/thread), B 1024 short8s (4/thread)
    int aRow[2], aOff[2];
#pragma unroll
    for (int j = 0; j < 2; ++j) {
        int idx = j * 256 + tid;
        aRow[j] = idx >> 3;
        aOff[j] = (idx >> 3) * LDP + (idx & 7) * 8;
    }
    int bRow[4], bOff[4];
#pragma unroll
    for (int j = 0; j < 4; ++j) {
        int idx = j * 256 + tid;
        bRow[j] = idx >> 3;
        bOff[j] = (idx >> 3) * LDP + (idx & 7) * 8;
    }
    const short8* gA[2]; const short8* gB[4];
#pragma unroll
    for (int j = 0; j < 2; ++j)
        gA[j] = (const short8*)(U + (size_t)(bm0 + aRow[j]) * ND) + ((aOff[j] - aRow[j] * LDP) >> 3);
#pragma unroll
    for (int j = 0; j < 4; ++j)
        gB[j] = (const short8*)(W2t + (size_t)(bn0 + bRow[j]) * ND) + ((bOff[j] - bRow[j] * LDP) >> 3);

    floatx4 acc[2][4];
#pragma unroll
    for (int m = 0; m < 2; ++m)
#pragma unroll
        for (int n = 0; n < 4; ++n) acc[m][n] = (floatx4){0.f, 0.f, 0.f, 0.f};

    short8 ra[2], rb[4];
#pragma unroll
    for (int j = 0; j < 2; ++j) ra[j] = gA[j][0];
#pragma unroll
    for (int j = 0; j < 4; ++j) rb[j] = gB[j][0];

    const int NT = ND / BK;   // 16
#pragma unroll 1
    for (int t = 0; t < NT; ++t) {
        __syncthreads();
#pragma unroll
        for (int j = 0; j < 2; ++j) *(short8*)&As[aOff[j]] = ra[j];
#pragma unroll
        for (int j = 0; j < 4; ++j) *(short8*)&Bs[bOff[j]] = rb[j];
        __syncthreads();
        if (t < NT - 1) {
#pragma unroll
            for (int j = 0; j < 2; ++j) ra[j] = gA[j][(t + 1) * 8];
#pragma unroll
            for (int j = 0; j < 4; ++j) rb[j] = gB[j][(t + 1) * 8];
        }
#pragma unroll
        for (int kk = 0; kk < 2; ++kk) {
            short8 a[2], b[4];
#pragma unroll
            for (int m = 0; m < 2; ++m)
                a[m] = *(const short8*)&As[(wr * 32 + m * 16 + lr) * LDP + kk * 32 + kh * 8];
#pragma unroll
            for (int n = 0; n < 4; ++n)
                b[n] = *(const short8*)&Bs[(wc * 64 + n * 16 + lr) * LDP + kk * 32 + kh * 8];
#pragma unroll
            for (int m = 0; m < 2; ++m)
#pragma unroll
                for (int n = 0; n < 4; ++n)
                    acc[m][n] = __builtin_amdgcn_mfma_f32_16x16x32_bf16(a[m], b[n], acc[m][n], 0, 0, 0);
        }
    }
#pragma unroll
    for (int m = 0; m < 2; ++m)
#pragma unroll
        for (int n = 0; n < 4; ++n)
#pragma unroll
            for (int r = 0; r < 4; ++r)
                V[(size_t)(bm0 + wr * 32 + m * 16 + kh * 4 + r) * ND + bn0 + wc * 64 + n * 16 + lr]
                    = f2bf(acc[m][n][r]);
}

// K3: stream all 12 layers per (b,s) row; LN-folded logits; softmax over depth;
// register-held weighted mix; gate; write out. V read as bf16.
__global__ void k_fused(const float* __restrict__ states, const unsigned short* __restrict__ V,
                        const float* __restrict__ lnw, const float* __restrict__ lnb,
                        const float* __restrict__ gatep, float* __restrict__ out) {
    __shared__ float s_logit[12];
    __shared__ float s_w12[12];
    __shared__ float s_g;
    __shared__ float s_part[4][ND];
    __shared__ float s_x11[ND];
    const int p = blockIdx.x;
    const int tid = threadIdx.x;
    const int lane = tid & 63;
    const int wv = tid >> 6;
    const size_t LS = (size_t)NBS * ND;
    const float* base = states + (size_t)p * ND;
    const short4v* Vp = (const short4v*)(V + (size_t)p * ND);

    float4 t[4];
    float red[11];
#pragma unroll
    for (int j = 0; j < 11; ++j) red[j] = 0.f;
#pragma unroll
    for (int i = 0; i < 4; ++i) {
        int idx = lane + 64 * i;
        short4v vq = Vp[idx];
        float4 v;
        v.x = bf2f(vq[0]); v.y = bf2f(vq[1]); v.z = bf2f(vq[2]); v.w = bf2f(vq[3]);
        float4 w = ((const float4*)lnw)[idx];
        float4 b = ((const float4*)lnb)[idx];
        float4 tt; tt.x = v.x*w.x; tt.y = v.y*w.y; tt.z = v.z*w.z; tt.w = v.w*w.w;
        t[i] = tt;
        red[9]  += tt.x + tt.y + tt.z + tt.w;
        red[10] += v.x*b.x + v.y*b.y + v.z*b.z + v.w*b.w;
    }

    float4 x[3][4];
#pragma unroll
    for (int rr = 0; rr < 3; ++rr) {
        const int l = wv + 4 * rr;
        const float4* xr = (const float4*)(base + (size_t)l * LS);
#pragma unroll
        for (int i = 0; i < 4; ++i) {
            float4 xx = xr[lane + 64 * i];
            x[rr][i] = xx;
            red[rr]     += xx.x + xx.y + xx.z + xx.w;
            red[3 + rr] += xx.x*xx.x + xx.y*xx.y + xx.z*xx.z + xx.w*xx.w;
            red[6 + rr] += xx.x*t[i].x + xx.y*t[i].y + xx.z*t[i].z + xx.w*t[i].w;
        }
    }
#pragma unroll
    for (int m = 32; m > 0; m >>= 1) {
#pragma unroll
        for (int j = 0; j < 11; ++j) red[j] += __shfl_xor(red[j], m);
    }
    if (lane == 0) {
#pragma unroll
        for (int rr = 0; rr < 3; ++rr) {
            float mu = red[rr] * (1.0f / ND);
            float var = red[3 + rr] * (1.0f / ND) - mu * mu;
            float rstd = rsqrtf(var + 1e-5f);
            s_logit[wv + 4 * rr] = 0.0625f * (rstd * (red[6 + rr] - mu * red[9]) + red[10]);
        }
    }
    __syncthreads();
    if (tid == 0) {
        float mx = s_logit[0];
#pragma unroll
        for (int l = 1; l < 12; ++l) mx = fmaxf(mx, s_logit[l]);
        float e[12], sum = 0.f;
#pragma unroll
        for (int l = 0; l < 12; ++l) { e[l] = expf(s_logit[l] - mx); sum += e[l]; }
        float inv = 1.0f / sum;
#pragma unroll
        for (int l = 0; l < 12; ++l) s_w12[l] = e[l] * inv;
        s_g = 1.0f / (1.0f + expf(-gatep[0]));
    }
    __syncthreads();

    const float w0 = s_w12[wv], w1 = s_w12[wv + 4], w2 = s_w12[wv + 8];
#pragma unroll
    for (int i = 0; i < 4; ++i) {
        int idx = lane + 64 * i;
        float4 pm;
        pm.x = w0*x[0][i].x + w1*x[1][i].x + w2*x[2][i].x;
        pm.y = w0*x[0][i].y + w1*x[1][i].y + w2*x[2][i].y;
        pm.z = w0*x[0][i].z + w1*x[1][i].z + w2*x[2][i].z;
        pm.w = w0*x[0][i].w + w1*x[1][i].w + w2*x[2][i].w;
        ((float4*)s_part[wv])[idx] = pm;
        if (wv == 3) ((float4*)s_x11)[idx] = x[2][i];   // wv=3, rr=2 -> l=11
    }
    __syncthreads();

    const float g = s_g;
    float4 a0 = ((const float4*)s_part[0])[tid];
    float4 a1 = ((const float4*)s_part[1])[tid];
    float4 a2 = ((const float4*)s_part[2])[tid];
    float4 a3 = ((const float4*)s_part[3])[tid];
    float4 x11 = ((const float4*)s_x11)[tid];
    float4 o;
    o.x = g * x11.x + (1.f - g) * (a0.x + a1.x + a2.x + a3.x);
    o.y = g * x11.y + (1.f - g) * (a0.y + a1.y + a2.y + a3.y);
    o.z = g * x11.z + (1.f - g) * (a0.z + a1.z + a2.z + a3.z);
    o.w = g * x11.w + (1.f - g) * (a0.w + a1.w + a2.w + a3.w);
    ((float4*)(out + (size_t)p * ND))[tid] = o;
}

extern "C" void kernel_launch(void* const* d_in, const int* in_sizes, int n_in,
                              void* d_out, int out_size, void* d_ws, size_t ws_size,
                              hipStream_t stream) {
    (void)in_sizes; (void)n_in; (void)out_size; (void)ws_size;
    const float* states = (const float*)d_in[0];
    const float* Wq     = (const float*)d_in[1];
    const float* Wk     = (const float*)d_in[2];
    const float* lnw    = (const float*)d_in[3];
    const float* lnb    = (const float*)d_in[4];
    const float* gate   = (const float*)d_in[5];
    float* out = (float*)d_out;
    char* ws = (char*)d_ws;

    unsigned short* U   = (unsigned short*)(ws);                // 8 MiB  (NBS x ND bf16)
    unsigned short* W2t = (unsigned short*)(ws + (9u << 20));   // 2 MiB  (ND x ND bf16)
    unsigned short* V   = (unsigned short*)(ws + (12u << 20));  // 8 MiB  (NBS x ND bf16)

    k_prep_ln<<<dim3(256 + NBS), dim3(256), 0, stream>>>(
        Wq, Wk, states + (size_t)(NL - 1) * NBS * ND, lnw, lnb, W2t, U);
    k_vgemm<<<dim3((NBS / BM) * (ND / BN)), dim3(256), 0, stream>>>(U, W2t, V);
    k_fused<<<dim3(NBS), dim3(256), 0, stream>>>(states, V, lnw, lnb, gate, out);
}

// Round 5
// 74.843 us; speedup vs baseline: 1.5478x; 1.0078x over previous
//
#include <hip/hip_runtime.h>

#define NL 12
#define NB 2
#define NS 2048
#define ND 1024
#define NDK 256
#define NBS (NB*NS)   // 4096

typedef __attribute__((ext_vector_type(8))) short short8;
typedef __attribute__((ext_vector_type(4))) short short4v;
typedef __attribute__((ext_vector_type(4))) float floatx4;

__device__ __forceinline__ unsigned short f2bf(float f) {
    unsigned int u = __float_as_uint(f);
    u += 0x7FFFu + ((u >> 16) & 1u);
    return (unsigned short)(u >> 16);
}
__device__ __forceinline__ short f2bfs(float f) { return (short)f2bf(f); }
__device__ __forceinline__ float bf2f(short s) {
    return __uint_as_float(((unsigned int)(unsigned short)s) << 16);
}

// K1: blocks [0,256): W2t[d][d'] = sum_k Wk[k][d]*Wq[k][d']  (bf16 out, MFMA)
//     blocks [256, 256+4096): LayerNorm(states[11]) -> U bf16
__global__ void k_prep_ln(const float* __restrict__ Wq, const float* __restrict__ Wk,
                          const float* __restrict__ x11,
                          const float* __restrict__ lnw, const float* __restrict__ lnb,
                          unsigned short* __restrict__ W2t, unsigned short* __restrict__ U) {
    const int tid = threadIdx.x;
    if (blockIdx.x < 256) {
        const int lane = tid & 63, wv = tid >> 6;
        const int wid = blockIdx.x * 4 + wv;      // 0..1023
        const int tm = wid >> 4;                  // d-tile (rows of W2t), 0..63
        const int tnb = wid & 15;                 // d'-tile (cols, 64 wide), 0..15
        const int lr = lane & 15, kh = lane >> 4;
        floatx4 acc[4];
#pragma unroll
        for (int c = 0; c < 4; ++c) acc[c] = (floatx4){0.f, 0.f, 0.f, 0.f};
#pragma unroll 2
        for (int kb = 0; kb < 8; ++kb) {
            const float* Ab = Wk + (size_t)(kb * 32 + kh * 8) * ND + tm * 16 + lr;
            const float* Bb = Wq + (size_t)(kb * 32 + kh * 8) * ND + tnb * 64 + lr;
            short8 a;
#pragma unroll
            for (int j = 0; j < 8; ++j) a[j] = f2bfs(Ab[(size_t)j * ND]);
#pragma unroll
            for (int c = 0; c < 4; ++c) {
                short8 b;
#pragma unroll
                for (int j = 0; j < 8; ++j) b[j] = f2bfs(Bb[(size_t)j * ND + c * 16]);
                acc[c] = __builtin_amdgcn_mfma_f32_16x16x32_bf16(a, b, acc[c], 0, 0, 0);
            }
        }
#pragma unroll
        for (int c = 0; c < 4; ++c)
#pragma unroll
            for (int r = 0; r < 4; ++r)
                W2t[(size_t)(tm * 16 + kh * 4 + r) * ND + tnb * 64 + c * 16 + lr] = f2bf(acc[c][r]);
        return;
    }
    __shared__ float red[8];
    const int p = blockIdx.x - 256;
    const float4* xr = (const float4*)(x11 + (size_t)p * ND);
    float4 x = xr[tid];
    float s1 = x.x + x.y + x.z + x.w;
    float s2 = x.x*x.x + x.y*x.y + x.z*x.z + x.w*x.w;
#pragma unroll
    for (int m = 32; m > 0; m >>= 1) { s1 += __shfl_xor(s1, m); s2 += __shfl_xor(s2, m); }
    int wv = tid >> 6;
    if ((tid & 63) == 0) { red[wv] = s1; red[4 + wv] = s2; }
    __syncthreads();
    float S1 = red[0] + red[1] + red[2] + red[3];
    float S2 = red[4] + red[5] + red[6] + red[7];
    float mu = S1 * (1.0f / ND);
    float var = S2 * (1.0f / ND) - mu * mu;
    float rstd = rsqrtf(var + 1e-5f);
    float4 w = ((const float4*)lnw)[tid];
    float4 b = ((const float4*)lnb)[tid];
    ushort4 u;
    u.x = f2bf((x.x - mu) * rstd * w.x + b.x);
    u.y = f2bf((x.y - mu) * rstd * w.y + b.y);
    u.z = f2bf((x.z - mu) * rstd * w.z + b.z);
    u.w = f2bf((x.w - mu) * rstd * w.w + b.w);
    ((ushort4*)U)[(size_t)p * (ND / 4) + tid] = u;
}

// K2: V (4096 x 1024 bf16) = U (4096 x 1024 bf16) @ W2t^T
// 64x128 tile, BK=64, double-buffered LDS, ONE barrier per K-tile,
// prefetch-to-reg issued right after the barrier (full tile of compute to hide).
// Epilogue: LDS-transpose staged coalesced bf16 stores.
#define BM 64
#define BN 128
#define BK 64
#define LDP 72    // padded LDS row (elements)
#define TLP 132   // padded epilogue row (elements)
__global__ __launch_bounds__(256) void k_vgemm(const unsigned short* __restrict__ U,
                                               const unsigned short* __restrict__ W2t,
                                               unsigned short* __restrict__ V) {
    __shared__ unsigned short As[2][BM * LDP];   // 18.4 KB
    __shared__ unsigned short Bs[2][BN * LDP];   // 36.9 KB
    const int tid = threadIdx.x;
    const int lane = tid & 63;
    const int wv = tid >> 6;
    const int wr = wv >> 1, wc = wv & 1;
    const int lr = lane & 15, kh = lane >> 4;
    const int bm0 = (blockIdx.x >> 3) * BM;   // 64 m-tiles
    const int bn0 = (blockIdx.x & 7) * BN;    // 8 n-tiles

    // staging maps: A 512 short8s (2/thread), B 1024 short8s (4/thread)
    int aOff[2], bOff[4];
    const short8* gA[2];
    const short8* gB[4];
#pragma unroll
    for (int j = 0; j < 2; ++j) {
        int idx = j * 256 + tid;
        int row = idx >> 3, c8 = idx & 7;
        aOff[j] = row * LDP + c8 * 8;
        gA[j] = (const short8*)(U + (size_t)(bm0 + row) * ND) + c8;
    }
#pragma unroll
    for (int j = 0; j < 4; ++j) {
        int idx = j * 256 + tid;
        int row = idx >> 3, c8 = idx & 7;
        bOff[j] = row * LDP + c8 * 8;
        gB[j] = (const short8*)(W2t + (size_t)(bn0 + row) * ND) + c8;
    }

    floatx4 acc[2][4];
#pragma unroll
    for (int m = 0; m < 2; ++m)
#pragma unroll
        for (int n = 0; n < 4; ++n) acc[m][n] = (floatx4){0.f, 0.f, 0.f, 0.f};

    short8 ra[2], rb[4];
#pragma unroll
    for (int j = 0; j < 2; ++j) ra[j] = gA[j][0];
#pragma unroll
    for (int j = 0; j < 4; ++j) rb[j] = gB[j][0];

    const int NT = ND / BK;   // 16
#pragma unroll 1
    for (int t = 0; t < NT; ++t) {
        unsigned short* Ab = As[t & 1];
        unsigned short* Bb = Bs[t & 1];
#pragma unroll
        for (int j = 0; j < 2; ++j) *(short8*)&Ab[aOff[j]] = ra[j];
#pragma unroll
        for (int j = 0; j < 4; ++j) *(short8*)&Bb[bOff[j]] = rb[j];
        __syncthreads();                       // single barrier per tile
        if (t < NT - 1) {                      // prefetch t+1 (lands during MFMA phase)
#pragma unroll
            for (int j = 0; j < 2; ++j) ra[j] = gA[j][(t + 1) * 8];
#pragma unroll
            for (int j = 0; j < 4; ++j) rb[j] = gB[j][(t + 1) * 8];
        }
#pragma unroll
        for (int kk = 0; kk < 2; ++kk) {
            short8 a[2], b[4];
#pragma unroll
            for (int m = 0; m < 2; ++m)
                a[m] = *(const short8*)&Ab[(wr * 32 + m * 16 + lr) * LDP + kk * 32 + kh * 8];
#pragma unroll
            for (int n = 0; n < 4; ++n)
                b[n] = *(const short8*)&Bb[(wc * 64 + n * 16 + lr) * LDP + kk * 32 + kh * 8];
#pragma unroll
            for (int m = 0; m < 2; ++m)
#pragma unroll
                for (int n = 0; n < 4; ++n)
                    acc[m][n] = __builtin_amdgcn_mfma_f32_16x16x32_bf16(a[m], b[n], acc[m][n], 0, 0, 0);
        }
    }

    // epilogue: stage C-tile (64x128 bf16) into LDS (reuse As), store coalesced
    __syncthreads();                            // all ds_reads of the loop done
    unsigned short* Cs = (unsigned short*)As;   // 64*TLP = 16.9 KB <= 18.4 KB
#pragma unroll
    for (int m = 0; m < 2; ++m)
#pragma unroll
        for (int n = 0; n < 4; ++n)
#pragma unroll
            for (int r = 0; r < 4; ++r)
                Cs[(wr * 32 + m * 16 + kh * 4 + r) * TLP + wc * 64 + n * 16 + lr] = f2bf(acc[m][n][r]);
    __syncthreads();
#pragma unroll
    for (int j = 0; j < 4; ++j) {
        int idx = j * 256 + tid;                // 1024 short8s = 64 rows x 16
        int row = idx >> 4, c8 = idx & 15;
        *(short8*)&V[(size_t)(bm0 + row) * ND + bn0 + c8 * 8] = *(const short8*)&Cs[row * TLP + c8 * 8];
    }
}

// K3: stream all 12 layers per (b,s) row; LN-folded logits; softmax over depth;
// register-held weighted mix; gate; write out. V read as bf16.
__global__ void k_fused(const float* __restrict__ states, const unsigned short* __restrict__ V,
                        const float* __restrict__ lnw, const float* __restrict__ lnb,
                        const float* __restrict__ gatep, float* __restrict__ out) {
    __shared__ float s_logit[12];
    __shared__ float s_w12[12];
    __shared__ float s_g;
    __shared__ float s_part[4][ND];
    __shared__ float s_x11[ND];
    const int p = blockIdx.x;
    const int tid = threadIdx.x;
    const int lane = tid & 63;
    const int wv = tid >> 6;
    const size_t LS = (size_t)NBS * ND;
    const float* base = states + (size_t)p * ND;
    const short4v* Vp = (const short4v*)(V + (size_t)p * ND);

    float4 t[4];
    float red[11];
#pragma unroll
    for (int j = 0; j < 11; ++j) red[j] = 0.f;
#pragma unroll
    for (int i = 0; i < 4; ++i) {
        int idx = lane + 64 * i;
        short4v vq = Vp[idx];
        float4 v;
        v.x = bf2f(vq[0]); v.y = bf2f(vq[1]); v.z = bf2f(vq[2]); v.w = bf2f(vq[3]);
        float4 w = ((const float4*)lnw)[idx];
        float4 b = ((const float4*)lnb)[idx];
        float4 tt; tt.x = v.x*w.x; tt.y = v.y*w.y; tt.z = v.z*w.z; tt.w = v.w*w.w;
        t[i] = tt;
        red[9]  += tt.x + tt.y + tt.z + tt.w;
        red[10] += v.x*b.x + v.y*b.y + v.z*b.z + v.w*b.w;
    }

    float4 x[3][4];
#pragma unroll
    for (int rr = 0; rr < 3; ++rr) {
        const int l = wv + 4 * rr;
        const float4* xr = (const float4*)(base + (size_t)l * LS);
#pragma unroll
        for (int i = 0; i < 4; ++i) {
            float4 xx = xr[lane + 64 * i];
            x[rr][i] = xx;
            red[rr]     += xx.x + xx.y + xx.z + xx.w;
            red[3 + rr] += xx.x*xx.x + xx.y*xx.y + xx.z*xx.z + xx.w*xx.w;
            red[6 + rr] += xx.x*t[i].x + xx.y*t[i].y + xx.z*t[i].z + xx.w*t[i].w;
        }
    }
#pragma unroll
    for (int m = 32; m > 0; m >>= 1) {
#pragma unroll
        for (int j = 0; j < 11; ++j) red[j] += __shfl_xor(red[j], m);
    }
    if (lane == 0) {
#pragma unroll
        for (int rr = 0; rr < 3; ++rr) {
            float mu = red[rr] * (1.0f / ND);
            float var = red[3 + rr] * (1.0f / ND) - mu * mu;
            float rstd = rsqrtf(var + 1e-5f);
            s_logit[wv + 4 * rr] = 0.0625f * (rstd * (red[6 + rr] - mu * red[9]) + red[10]);
        }
    }
    __syncthreads();
    if (tid == 0) {
        float mx = s_logit[0];
#pragma unroll
        for (int l = 1; l < 12; ++l) mx = fmaxf(mx, s_logit[l]);
        float e[12], sum = 0.f;
#pragma unroll
        for (int l = 0; l < 12; ++l) { e[l] = expf(s_logit[l] - mx); sum += e[l]; }
        float inv = 1.0f / sum;
#pragma unroll
        for (int l = 0; l < 12; ++l) s_w12[l] = e[l] * inv;
        s_g = 1.0f / (1.0f + expf(-gatep[0]));
    }
    __syncthreads();

    const float w0 = s_w12[wv], w1 = s_w12[wv + 4], w2 = s_w12[wv + 8];
#pragma unroll
    for (int i = 0; i < 4; ++i) {
        int idx = lane + 64 * i;
        float4 pm;
        pm.x = w0*x[0][i].x + w1*x[1][i].x + w2*x[2][i].x;
        pm.y = w0*x[0][i].y + w1*x[1][i].y + w2*x[2][i].y;
        pm.z = w0*x[0][i].z + w1*x[1][i].z + w2*x[2][i].z;
        pm.w = w0*x[0][i].w + w1*x[1][i].w + w2*x[2][i].w;
        ((float4*)s_part[wv])[idx] = pm;
        if (wv == 3) ((float4*)s_x11)[idx] = x[2][i];   // wv=3, rr=2 -> l=11
    }
    __syncthreads();

    const float g = s_g;
    float4 a0 = ((const float4*)s_part[0])[tid];
    float4 a1 = ((const float4*)s_part[1])[tid];
    float4 a2 = ((const float4*)s_part[2])[tid];
    float4 a3 = ((const float4*)s_part[3])[tid];
    float4 x11 = ((const float4*)s_x11)[tid];
    float4 o;
    o.x = g * x11.x + (1.f - g) * (a0.x + a1.x + a2.x + a3.x);
    o.y = g * x11.y + (1.f - g) * (a0.y + a1.y + a2.y + a3.y);
    o.z = g * x11.z + (1.f - g) * (a0.z + a1.z + a2.z + a3.z);
    o.w = g * x11.w + (1.f - g) * (a0.w + a1.w + a2.w + a3.w);
    ((float4*)(out + (size_t)p * ND))[tid] = o;
}

extern "C" void kernel_launch(void* const* d_in, const int* in_sizes, int n_in,
                              void* d_out, int out_size, void* d_ws, size_t ws_size,
                              hipStream_t stream) {
    (void)in_sizes; (void)n_in; (void)out_size; (void)ws_size;
    const float* states = (const float*)d_in[0];
    const float* Wq     = (const float*)d_in[1];
    const float* Wk     = (const float*)d_in[2];
    const float* lnw    = (const float*)d_in[3];
    const float* lnb    = (const float*)d_in[4];
    const float* gate   = (const float*)d_in[5];
    float* out = (float*)d_out;
    char* ws = (char*)d_ws;

    unsigned short* U   = (unsigned short*)(ws);                // 8 MiB  (NBS x ND bf16)
    unsigned short* W2t = (unsigned short*)(ws + (9u << 20));   // 2 MiB  (ND x ND bf16)
    unsigned short* V   = (unsigned short*)(ws + (12u << 20));  // 8 MiB  (NBS x ND bf16)

    k_prep_ln<<<dim3(256 + NBS), dim3(256), 0, stream>>>(
        Wq, Wk, states + (size_t)(NL - 1) * NBS * ND, lnw, lnb, W2t, U);
    k_vgemm<<<dim3((NBS / BM) * (ND / BN)), dim3(256), 0, stream>>>(U, W2t, V);
    k_fused<<<dim3(NBS), dim3(256), 0, stream>>>(states, V, lnw, lnb, gate, out);
}